// Round 1
// baseline (702.076 us; speedup 1.0000x reference)
//
#include <hip/hip_runtime.h>
#include <hip/hip_bf16.h>
#include <math.h>

#define NROWS 32768
#define DD 16
#define HH 128
#define ENT 50000

// ws layout (floats):
static const size_t OFF_PE  = 0;                  // [50000][256]
static const size_t OFF_WA  = (size_t)ENT * 256;  // [128][256] k-major acc-weights
static const size_t OFF_PEW = OFF_WA + 32768;     // [128][256] k-major ent-weights
static const size_t OFF_PO  = OFF_PEW + 32768;    // [5][256] op contrib + bias folded

__device__ __forceinline__ int sw_idx(int k, int r) {
    // float-index XOR swizzle: spreads writes across banks, reads stay broadcast
    return (k * 64 + r) ^ (((k >> 2) & 7) << 2);
}

// ---------------- prep: build WaKM, PEW, PO, copy non_table ----------------
__global__ void prep_kernel(const float* __restrict__ op_table,
                            const float* __restrict__ non_table,
                            const float* __restrict__ Wm, const float* __restrict__ bm,
                            const float* __restrict__ Wg, const float* __restrict__ bg,
                            float* __restrict__ ws, float* __restrict__ out) {
    int idx = blockIdx.x * blockDim.x + threadIdx.x;
    if (idx < 32768) {                       // WaKM[k][j] = W*[j, 256+k]
        int k = idx >> 8, j = idx & 255;
        float v = (j < 128) ? Wm[j * 384 + 256 + k] : Wg[(j - 128) * 384 + 256 + k];
        ws[OFF_WA + idx] = v;
    } else if (idx < 65536) {                // PEW[k][j] = W*[j, 128+k]
        int t = idx - 32768;
        int k = t >> 8, j = t & 255;
        float v = (j < 128) ? Wm[j * 384 + 128 + k] : Wg[(j - 128) * 384 + 128 + k];
        ws[OFF_PEW + t] = v;
    } else if (idx < 66816) {                // PO[o][j] = op[o]@W*[j,0:128] + b*[j]
        int t = idx - 65536;
        int o = t >> 8, j = t & 255;
        const float* Wrow = (j < 128) ? (Wm + (size_t)j * 384) : (Wg + (size_t)(j - 128) * 384);
        float s = (j < 128) ? bm[j] : bg[j - 128];
        for (int i = 0; i < 128; ++i) s += op_table[o * 128 + i] * Wrow[i];
        ws[OFF_PO + t] = s;
    } else if (idx < 66944) {                // out row N = non_table
        int j = idx - 66816;
        out[(size_t)NROWS * 128 + j] = non_table[j];
    }
}

// ---------------- PE = ent_table @ PEW  (50000 x 256) ----------------
__global__ __launch_bounds__(512, 2)
void pe_kernel(const float* __restrict__ ent_table, float* __restrict__ ws) {
    extern __shared__ float lds[];
    float* Ws = lds;           // [128][256]
    float* aT = lds + 32768;   // [128][64] swizzled
    const float* PEW = ws + OFF_PEW;
    float* PE = ws + OFF_PE;
    int tid = threadIdx.x;
    int e0 = blockIdx.x * 64;

    #pragma unroll
    for (int c = 0; c < 16; ++c) {
        int i = tid + 512 * c;
        reinterpret_cast<float4*>(Ws)[i] = reinterpret_cast<const float4*>(PEW)[i];
    }
    {
        int r = tid >> 3, sub = tid & 7;
        int e = e0 + r;
        if (e < ENT) {
            const float4* src = reinterpret_cast<const float4*>(ent_table + (size_t)e * 128 + sub * 16);
            #pragma unroll
            for (int i4 = 0; i4 < 4; ++i4) {
                float4 v = src[i4];
                int kb = sub * 16 + i4 * 4;
                aT[sw_idx(kb + 0, r)] = v.x;
                aT[sw_idx(kb + 1, r)] = v.y;
                aT[sw_idx(kb + 2, r)] = v.z;
                aT[sw_idx(kb + 3, r)] = v.w;
            }
        } else {
            #pragma unroll
            for (int i4 = 0; i4 < 16; ++i4) aT[sw_idx(sub * 16 + i4, r)] = 0.f;
        }
    }
    __syncthreads();

    int rg = tid >> 5, cg = tid & 31;
    int r0 = rg * 4, c0 = cg * 4;
    float zm[4][4] = {{0}}, zg[4][4] = {{0}};

    #pragma unroll 4
    for (int k = 0; k < 128; ++k) {
        float4 a  = *reinterpret_cast<const float4*>(&aT[sw_idx(k, r0)]);
        float4 wm = *reinterpret_cast<const float4*>(&Ws[(k << 8) + c0]);
        float4 wg = *reinterpret_cast<const float4*>(&Ws[(k << 8) + 128 + c0]);
        float av[4]  = {a.x, a.y, a.z, a.w};
        float wmv[4] = {wm.x, wm.y, wm.z, wm.w};
        float wgv[4] = {wg.x, wg.y, wg.z, wg.w};
        #pragma unroll
        for (int rr = 0; rr < 4; ++rr)
            #pragma unroll
            for (int cc = 0; cc < 4; ++cc) {
                zm[rr][cc] = fmaf(av[rr], wmv[cc], zm[rr][cc]);
                zg[rr][cc] = fmaf(av[rr], wgv[cc], zg[rr][cc]);
            }
    }
    #pragma unroll
    for (int rr = 0; rr < 4; ++rr) {
        int e2 = e0 + r0 + rr;
        if (e2 < ENT) {
            float4 m = make_float4(zm[rr][0], zm[rr][1], zm[rr][2], zm[rr][3]);
            float4 g = make_float4(zg[rr][0], zg[rr][1], zg[rr][2], zg[rr][3]);
            *reinterpret_cast<float4*>(&PE[(size_t)e2 * 256 + c0]) = m;
            *reinterpret_cast<float4*>(&PE[(size_t)e2 * 256 + 128 + c0]) = g;
        }
    }
}

// ---------------- fused 17-step chain ----------------
__global__ __launch_bounds__(512, 2)
void chain_kernel(const float* __restrict__ ent_table,
                  const int* __restrict__ ops_idx,
                  const int* __restrict__ ents_idx,
                  const int* __restrict__ left_idx,
                  const float* __restrict__ ws, float* __restrict__ out) {
    extern __shared__ float lds[];
    float* Ws = lds;           // [128][256]
    float* aT = lds + 32768;   // [128][64] swizzled (acc, k-major)
    const float* WaKM = ws + OFF_WA;
    const float* PE = ws + OFF_PE;
    const float* PO = ws + OFF_PO;
    int tid = threadIdx.x;
    int row0 = blockIdx.x * 64;

    #pragma unroll
    for (int c = 0; c < 16; ++c) {
        int i = tid + 512 * c;
        reinterpret_cast<float4*>(Ws)[i] = reinterpret_cast<const float4*>(WaKM)[i];
    }
    {   // acc0 = ent_table[ents_idx[row][16]]
        int r = tid >> 3, sub = tid & 7;
        int row = row0 + r;
        int e = ents_idx[row * 17 + 16];
        const float4* src = reinterpret_cast<const float4*>(ent_table + (size_t)e * 128 + sub * 16);
        #pragma unroll
        for (int i4 = 0; i4 < 4; ++i4) {
            float4 v = src[i4];
            int kb = sub * 16 + i4 * 4;
            aT[sw_idx(kb + 0, r)] = v.x;
            aT[sw_idx(kb + 1, r)] = v.y;
            aT[sw_idx(kb + 2, r)] = v.z;
            aT[sw_idx(kb + 3, r)] = v.w;
        }
    }
    __syncthreads();

    int rg = tid >> 5, cg = tid & 31;
    int r0 = rg * 4, c0 = cg * 4;

    for (int t = 0; t < 17; ++t) {
        // issue gathers early; consumed after the FMA loop (latency hidden)
        float4 pem[4], peg[4], pom[4], pog[4];
        #pragma unroll
        for (int rr = 0; rr < 4; ++rr) {
            int row = row0 + r0 + rr;
            int e, o;
            if (t < 16) {
                e = ents_idx[row * 17 + (15 - t)];
                o = ops_idx[row * 16 + (15 - t)];
            } else {
                e = left_idx[row];
                o = 4;
            }
            pem[rr] = *reinterpret_cast<const float4*>(&PE[(size_t)e * 256 + c0]);
            peg[rr] = *reinterpret_cast<const float4*>(&PE[(size_t)e * 256 + 128 + c0]);
            pom[rr] = *reinterpret_cast<const float4*>(&PO[o * 256 + c0]);
            pog[rr] = *reinterpret_cast<const float4*>(&PO[o * 256 + 128 + c0]);
        }

        float zm[4][4] = {{0}}, zg[4][4] = {{0}};
        #pragma unroll 4
        for (int k = 0; k < 128; ++k) {
            float4 a  = *reinterpret_cast<const float4*>(&aT[sw_idx(k, r0)]);
            float4 wm = *reinterpret_cast<const float4*>(&Ws[(k << 8) + c0]);
            float4 wg = *reinterpret_cast<const float4*>(&Ws[(k << 8) + 128 + c0]);
            float av[4]  = {a.x, a.y, a.z, a.w};
            float wmv[4] = {wm.x, wm.y, wm.z, wm.w};
            float wgv[4] = {wg.x, wg.y, wg.z, wg.w};
            #pragma unroll
            for (int rr = 0; rr < 4; ++rr)
                #pragma unroll
                for (int cc = 0; cc < 4; ++cc) {
                    zm[rr][cc] = fmaf(av[rr], wmv[cc], zm[rr][cc]);
                    zg[rr][cc] = fmaf(av[rr], wgv[cc], zg[rr][cc]);
                }
        }

        // combine + activation: acc_new = tanh(zm+pre_m) * sigmoid(zg+pre_g)
        float an[4][4];
        #pragma unroll
        for (int rr = 0; rr < 4; ++rr) {
            float pmv[4] = {pem[rr].x + pom[rr].x, pem[rr].y + pom[rr].y,
                            pem[rr].z + pom[rr].z, pem[rr].w + pom[rr].w};
            float pgv[4] = {peg[rr].x + pog[rr].x, peg[rr].y + pog[rr].y,
                            peg[rr].z + pog[rr].z, peg[rr].w + pog[rr].w};
            #pragma unroll
            for (int cc = 0; cc < 4; ++cc) {
                float m = zm[rr][cc] + pmv[cc];
                float g = zg[rr][cc] + pgv[cc];
                float e2 = __expf(2.f * m);
                float th = (e2 - 1.f) / (e2 + 1.f);
                float sg = 1.f / (1.f + __expf(-g));
                an[rr][cc] = th * sg;
            }
        }

        __syncthreads();  // all waves done reading old acc
        if (t < 16) {
            #pragma unroll
            for (int cc = 0; cc < 4; ++cc) {
                float4 v = make_float4(an[0][cc], an[1][cc], an[2][cc], an[3][cc]);
                *reinterpret_cast<float4*>(&aT[sw_idx(c0 + cc, r0)]) = v;
            }
        } else {
            #pragma unroll
            for (int rr = 0; rr < 4; ++rr) {
                float4 v = make_float4(an[rr][0], an[rr][1], an[rr][2], an[rr][3]);
                *reinterpret_cast<float4*>(&out[(size_t)(row0 + r0 + rr) * 128 + c0]) = v;
            }
        }
        __syncthreads();  // writes visible before next step
    }
}

extern "C" void kernel_launch(void* const* d_in, const int* in_sizes, int n_in,
                              void* d_out, int out_size, void* d_ws, size_t ws_size,
                              hipStream_t stream) {
    const float* ent_table = (const float*)d_in[0];
    const float* op_table  = (const float*)d_in[1];
    const float* non_table = (const float*)d_in[2];
    const float* Wm        = (const float*)d_in[3];
    const float* bm        = (const float*)d_in[4];
    const float* Wg        = (const float*)d_in[5];
    const float* bg        = (const float*)d_in[6];
    const int* ops_idx     = (const int*)d_in[7];
    const int* ents_idx    = (const int*)d_in[8];
    const int* left_idx    = (const int*)d_in[9];
    float* out = (float*)d_out;
    float* ws  = (float*)d_ws;

    prep_kernel<<<262, 256, 0, stream>>>(op_table, non_table, Wm, bm, Wg, bg, ws, out);
    pe_kernel<<<782, 512, 163840, stream>>>(ent_table, ws);
    chain_kernel<<<512, 512, 163840, stream>>>(ent_table, ops_idx, ents_idx, left_idx, ws, out);
}

// Round 2
// 249.352 us; speedup vs baseline: 2.8156x; 2.8156x over previous
//
#include <hip/hip_runtime.h>
#include <hip/hip_bf16.h>

#define NROWS 32768
#define HH 128
#define ENTN 50000
#define BM 32

typedef short bf16x8 __attribute__((ext_vector_type(8)));
typedef float f32x4 __attribute__((ext_vector_type(4)));

// ws byte offsets
#define OFF_EB 0                               // bf16 [50000][128]
#define OFF_WF (ENTN * HH * 2)                 // bf16 [8][2][12][64][8] frag-ordered
#define OFF_PO (OFF_WF + 8*2*12*64*8*2)        // f32  [5][256]

__device__ __forceinline__ unsigned short f2bf(float x) {
    unsigned u = __float_as_uint(x);
    return (unsigned short)((u + 0x7FFFu + ((u >> 16) & 1u)) >> 16);
}
__device__ __forceinline__ float bf2f(unsigned short h) {
    return __uint_as_float(((unsigned)h) << 16);
}

// ---------------- prep: EB (bf16 ent table), WF (W fragments), PO, out tail ----------------
__global__ void prep_kernel(const float* __restrict__ ent_table,
                            const float* __restrict__ op_table,
                            const float* __restrict__ non_table,
                            const float* __restrict__ Wm, const float* __restrict__ bm,
                            const float* __restrict__ Wg, const float* __restrict__ bg,
                            char* __restrict__ ws, float* __restrict__ out) {
    int idx = blockIdx.x * blockDim.x + threadIdx.x;
    unsigned short* EB = (unsigned short*)(ws + OFF_EB);
    unsigned short* WF = (unsigned short*)(ws + OFF_WF);
    float* PO = (float*)(ws + OFF_PO);
    if (idx < 800000) {                          // EB: 8 elems/thread
        int base = idx * 8;
        const float4* s = (const float4*)(ent_table + base);
        float4 v0 = s[0], v1 = s[1];
        float xv[8] = {v0.x, v0.y, v0.z, v0.w, v1.x, v1.y, v1.z, v1.w};
        unsigned short h8[8];
        #pragma unroll
        for (int j = 0; j < 8; ++j) h8[j] = f2bf(xv[j]);
        *(bf16x8*)(EB + base) = *(bf16x8*)h8;
    } else if (idx < 800000 + 98304) {           // WF frag-exact weights
        int t2 = idx - 800000;
        int j = t2 & 7;
        int lane = (t2 >> 3) & 63;
        int rest = t2 >> 9;
        int f = rest % 12;
        int wc = rest / 12;
        int ct = wc & 1, w = wc >> 1;
        int col = (ct ? 128 : 0) + 16 * w + (lane & 15);
        int krel = (f & 3) * 32 + (lane >> 4) * 8 + j;
        int kin = (f < 4) ? (128 + krel) : (256 + krel);
        const float* Wrow = (col < 128) ? (Wm + (size_t)col * 384)
                                        : (Wg + (size_t)(col - 128) * 384);
        float x = Wrow[kin];
        unsigned short h = f2bf(x);
        unsigned short v = (f < 8) ? h : f2bf(x - bf2f(h));
        WF[t2] = v;
    } else if (idx < 800000 + 98304 + 1280) {    // PO[o][j] = op[o]@W[j,0:128] + bias
        int t2 = idx - 898304;
        int o = t2 >> 8, j = t2 & 255;
        const float* Wrow = (j < 128) ? (Wm + (size_t)j * 384)
                                      : (Wg + (size_t)(j - 128) * 384);
        float s = (j < 128) ? bm[j] : bg[j - 128];
        for (int i = 0; i < 128; ++i) s += op_table[o * HH + i] * Wrow[i];
        PO[t2] = s;
    } else if (idx < 800000 + 98304 + 1280 + 128) {
        int j = idx - 899584;
        out[(size_t)NROWS * HH + j] = non_table[j];
    }
}

// ---------------- fused 17-step chain, MFMA ----------------
__global__ __launch_bounds__(512, 2)
void chain_kernel(const float* __restrict__ ent_table,
                  const int* __restrict__ ops_idx,
                  const int* __restrict__ ents_idx,
                  const int* __restrict__ left_idx,
                  const char* __restrict__ ws, float* __restrict__ out) {
    __shared__ char Abuf[16384];   // Ah [0,8192), Al [8192,16384), XOR-swizzled
    __shared__ float po_s[1280];
    __shared__ int eidx_s[BM * 17];
    __shared__ int oidx_s[BM * 16];
    __shared__ int lidx_s[BM];

    const unsigned short* EB = (const unsigned short*)(ws + OFF_EB);
    const bf16x8* WFp = (const bf16x8*)(ws + OFF_WF);
    const float* POg = (const float*)(ws + OFF_PO);

    int tid = threadIdx.x;
    int w = tid >> 6, l = tid & 63;
    int lr = l & 15, lg = l >> 4;
    int row0 = blockIdx.x * BM;

    for (int i = tid; i < BM * 17; i += 512) eidx_s[i] = ents_idx[row0 * 17 + i];
    if (tid < BM * 16) oidx_s[tid] = ops_idx[row0 * 16 + tid];
    if (tid < BM) lidx_s[tid] = left_idx[row0 + tid];
    for (int i = tid; i < 1280; i += 512) po_s[i] = POg[i];

    // per-wave weight fragments (registers)
    bf16x8 WE[2][4], WH[2][4], WL[2][4];
    #pragma unroll
    for (int ct = 0; ct < 2; ++ct) {
        int base = ((w * 2 + ct) * 12) * 64 + l;
        #pragma unroll
        for (int f = 0; f < 4; ++f) WE[ct][f] = WFp[base + f * 64];
        #pragma unroll
        for (int f = 0; f < 4; ++f) WH[ct][f] = WFp[base + (4 + f) * 64];
        #pragma unroll
        for (int f = 0; f < 4; ++f) WL[ct][f] = WFp[base + (8 + f) * 64];
    }

    // acc0 = ent_table[ents_idx[row][16]] -> hi/lo bf16 into swizzled LDS
    {
        int r = w * 4 + lg;          // 8 waves x 4 rows = 32
        int k0 = lr * 8;
        int e = ents_idx[(row0 + r) * 17 + 16];
        const float4* src = (const float4*)(ent_table + (size_t)e * HH + k0);
        float4 v0 = src[0], v1 = src[1];
        float xv[8] = {v0.x, v0.y, v0.z, v0.w, v1.x, v1.y, v1.z, v1.w};
        unsigned short h8[8], l8[8];
        #pragma unroll
        for (int j = 0; j < 8; ++j) {
            h8[j] = f2bf(xv[j]);
            l8[j] = f2bf(xv[j] - bf2f(h8[j]));
        }
        int byt = ((r << 8) + (k0 << 1)) ^ ((r & 7) << 4);
        *(bf16x8*)(Abuf + byt) = *(bf16x8*)h8;
        *(bf16x8*)(Abuf + 8192 + byt) = *(bf16x8*)l8;
    }
    __syncthreads();

    int cbase = 16 * w + lr;         // this lane's m-column; g-column = 128 + cbase

    for (int t = 0; t < 17; ++t) {
        int tt = 15 - t;
        // E gather (issued early; consumed by the last MFMA group)
        bf16x8 E[2][4];
        #pragma unroll
        for (int rt = 0; rt < 2; ++rt) {
            int r = 16 * rt + lr;
            int e = (t < 16) ? eidx_s[r * 17 + tt] : lidx_s[r];
            const bf16x8* ep = (const bf16x8*)(EB + (size_t)e * HH + lg * 8);
            #pragma unroll
            for (int kt = 0; kt < 4; ++kt) E[rt][kt] = ep[kt * 4];
        }

        f32x4 C[2][2];
        #pragma unroll
        for (int rt = 0; rt < 2; ++rt)
            #pragma unroll
            for (int ct = 0; ct < 2; ++ct) C[rt][ct] = (f32x4){0.f, 0.f, 0.f, 0.f};

        // acc path: AhWh + AlWh + AhWl
        #pragma unroll
        for (int kt = 0; kt < 4; ++kt) {
            bf16x8 AH[2], AL[2];
            #pragma unroll
            for (int rt = 0; rt < 2; ++rt) {
                int r = 16 * rt + lr;
                int byt = ((r << 8) + ((kt * 32 + lg * 8) << 1)) ^ ((r & 7) << 4);
                AH[rt] = *(const bf16x8*)(Abuf + byt);
                AL[rt] = *(const bf16x8*)(Abuf + 8192 + byt);
            }
            #pragma unroll
            for (int rt = 0; rt < 2; ++rt)
                #pragma unroll
                for (int ct = 0; ct < 2; ++ct) {
                    C[rt][ct] = __builtin_amdgcn_mfma_f32_16x16x32_bf16(AH[rt], WH[ct][kt], C[rt][ct], 0, 0, 0);
                    C[rt][ct] = __builtin_amdgcn_mfma_f32_16x16x32_bf16(AL[rt], WH[ct][kt], C[rt][ct], 0, 0, 0);
                    C[rt][ct] = __builtin_amdgcn_mfma_f32_16x16x32_bf16(AH[rt], WL[ct][kt], C[rt][ct], 0, 0, 0);
                }
        }
        // ent path (single bf16)
        #pragma unroll
        for (int kt = 0; kt < 4; ++kt)
            #pragma unroll
            for (int rt = 0; rt < 2; ++rt)
                #pragma unroll
                for (int ct = 0; ct < 2; ++ct)
                    C[rt][ct] = __builtin_amdgcn_mfma_f32_16x16x32_bf16(E[rt][kt], WE[ct][kt], C[rt][ct], 0, 0, 0);

        // activation: acc = tanh(m) * sigmoid(g)
        float av[2][4];
        #pragma unroll
        for (int rt = 0; rt < 2; ++rt)
            #pragma unroll
            for (int i = 0; i < 4; ++i) {
                int r2 = 16 * rt + 4 * lg + i;
                int o = (t < 16) ? oidx_s[r2 * 16 + tt] : 4;
                float m = C[rt][0][i] + po_s[o * 256 + cbase];
                float g = C[rt][1][i] + po_s[o * 256 + 128 + cbase];
                float e2 = __expf(2.f * m);
                float th = (e2 - 1.f) * __builtin_amdgcn_rcpf(e2 + 1.f);
                float sg = __builtin_amdgcn_rcpf(1.f + __expf(-g));
                av[rt][i] = th * sg;
            }

        if (t < 16) {
            __syncthreads();   // all waves done reading old acc
            #pragma unroll
            for (int rt = 0; rt < 2; ++rt)
                #pragma unroll
                for (int i = 0; i < 4; ++i) {
                    int r2 = 16 * rt + 4 * lg + i;
                    unsigned short h = f2bf(av[rt][i]);
                    unsigned short lo = f2bf(av[rt][i] - bf2f(h));
                    int byt = ((r2 << 8) + (cbase << 1)) ^ ((r2 & 7) << 4);
                    *(unsigned short*)(Abuf + byt) = h;
                    *(unsigned short*)(Abuf + 8192 + byt) = lo;
                }
            __syncthreads();   // writes visible before next step's reads
        } else {
            #pragma unroll
            for (int rt = 0; rt < 2; ++rt)
                #pragma unroll
                for (int i = 0; i < 4; ++i) {
                    int r2 = 16 * rt + 4 * lg + i;
                    out[(size_t)(row0 + r2) * HH + cbase] = av[rt][i];
                }
        }
    }
}

extern "C" void kernel_launch(void* const* d_in, const int* in_sizes, int n_in,
                              void* d_out, int out_size, void* d_ws, size_t ws_size,
                              hipStream_t stream) {
    const float* ent_table = (const float*)d_in[0];
    const float* op_table  = (const float*)d_in[1];
    const float* non_table = (const float*)d_in[2];
    const float* Wm        = (const float*)d_in[3];
    const float* bm        = (const float*)d_in[4];
    const float* Wg        = (const float*)d_in[5];
    const float* bg        = (const float*)d_in[6];
    const int* ops_idx     = (const int*)d_in[7];
    const int* ents_idx    = (const int*)d_in[8];
    const int* left_idx    = (const int*)d_in[9];
    float* out = (float*)d_out;
    char* ws = (char*)d_ws;

    prep_kernel<<<3516, 256, 0, stream>>>(ent_table, op_table, non_table,
                                          Wm, bm, Wg, bg, ws, out);
    chain_kernel<<<NROWS / BM, 512, 0, stream>>>(ent_table, ops_idx, ents_idx,
                                                 left_idx, ws, out);
}